// Round 1
// baseline (67.849 us; speedup 1.0000x reference)
//
#include <hip/hip_runtime.h>
#include <stdint.h>

// out[m,p] = sum_k f32(bits(x[m,k]) + bits(weight[p,k]) - OFFSET) + bias[p]
// m=256, n=512, p=512. Pure VALU workload (uint add on bit patterns -> no MFMA).
//
// R6: single dispatch, no k-split, no atomics, no memset.
//  - Grid 32x8 = 256 blocks (BP=64, BM=8, TM=2), exactly 1 block/CU.
//    Each block owns its 8x64 output tile end-to-end -> plain coalesced
//    stores; d_out needs no zeroing -> the hipMemsetAsync dispatch
//    (~1.5-2us of launch overhead) and the 524K-atomicAdd tail are gone.
//  - w tile [64][512] staged in 4 chunks of 32KB into 4 distinct LDS
//    buffers (128KB total) via global_load_lds width=16 (async DMA, no
//    VGPR round-trip). Chunk c+1 is issued right after the barrier for
//    chunk c, so its HBM/L2 latency hides under compute(c); the implicit
//    vmcnt(0) in the NEXT __syncthreads drains it. Only chunk 0 is exposed.
//  - gll writes LDS linearly (wave base + lane*16), so the conflict-free
//    XOR swizzle is applied on the GLOBAL source address (both-sides rule):
//    LDS[row][g] holds w-granule (g ^ (row&7)); reads use granule (j^rot),
//    rot = p_local&7 -> same measured-0-conflict pattern as R5 (512B rows).
//  - OFFSET fold moved from staged w (gll can't transform data) to the
//    wave-uniform x values: (a - OFFSET) is SALU, free beside the VALU.
//  - 4 waves/block, 1/SIMD: 8 independent acc chains + unroll-8 ds_read
//    lookahead cover latency without a second resident block.
//
// Measurement context: ~60us of dur_us is fixed harness cost (268MB ws
// re-poison = 40us at 84% HBM peak, + restores). Controllable chain was
// ~4.4us (memset dispatch + kernel w/ atomics); this version targets ~2.5us.

#define OFFSET_FP32 1064828928u

constexpr int M = 256;
constexpr int N = 512;
constexpr int P = 512;

constexpr int BP = 64;      // p cols per block
constexpr int BM = 8;       // m rows per block
constexpr int TM = 2;       // m rows per thread (one wave quad per TM rows)
constexpr int KC = 128;     // k per chunk
constexpr int NC = N / KC;  // 4 chunks, 4 distinct LDS buffers

__global__ __launch_bounds__(256) void lmul_linear_kernel(
    const uint32_t* __restrict__ xb,   // [M][N] bit patterns of x
    const uint32_t* __restrict__ wb,   // [P][N] bit patterns of weight
    const float*    __restrict__ bias, // [P]
    float*          __restrict__ out)  // [M][P]
{
    __shared__ uint32_t Bs[NC][BP][KC];   // 4 * 64 * 128 * 4B = 128 KB

    const int tid     = threadIdx.x;
    const int p_local = tid & (BP - 1);                            // 0..63
    const int wq      = __builtin_amdgcn_readfirstlane(tid >> 6);  // wave 0..3

    const int p0 = blockIdx.y * BP;
    const int m0 = blockIdx.x * BM + wq * TM;

    const int lane  = tid & 63;
    const int gran  = lane & 31;   // 16B granule within a 512B row
    const int rhalf = lane >> 5;   // each 1KB gll call covers 2 rows

    // ---- stage chunk c: 32KB = 32 x 1KB gll calls; wave wq stages rows
    //      wq*16 .. wq*16+15 (call i -> rows 2i, 2i+1 of its range) ----
    auto stage = [&](int c) {
        #pragma unroll
        for (int i = 0; i < 8; ++i) {
            const int row = wq * 16 + i * 2 + rhalf;
            // source granule pre-swizzled so linear LDS write lands swizzled
            const uint32_t* src = wb + (size_t)(p0 + row) * N + c * KC
                                     + ((gran ^ (row & 7)) * 4);
            uint32_t* dst = &Bs[c][wq * 16 + i * 2][0];   // wave-uniform base
            __builtin_amdgcn_global_load_lds(
                (const __attribute__((address_space(1))) uint32_t*)src,
                (__attribute__((address_space(3))) uint32_t*)dst,
                16, 0, 0);
        }
    };

    float acc[TM][4] = {};
    const int rot = p_local & 7;

    stage(0);
    __syncthreads();   // implicit vmcnt(0): chunk 0 resident

    #pragma unroll
    for (int c = 0; c < NC; ++c) {
        if (c + 1 < NC) stage(c + 1);   // async, hides under compute(c)

        const uint32_t* brow = &Bs[c][p_local][0];
        const uint32_t* xr0  = xb + (size_t)(m0 + 0) * N + c * KC;
        const uint32_t* xr1  = xb + (size_t)(m0 + 1) * N + c * KC;

        // 32 steps x (1 ds_read_b128 + 2 uniform uint4 a-loads + 16 VALU)
        #pragma unroll 8
        for (int j = 0; j < KC / 4; ++j) {
            const uint4 b  = *(const uint4*)&brow[(j ^ rot) * 4];
            const uint4 a0 = *(const uint4*)(xr0 + j * 4);  // uniform -> s_load
            const uint4 a1 = *(const uint4*)(xr1 + j * 4);
            acc[0][0] += __uint_as_float((a0.x - OFFSET_FP32) + b.x);
            acc[0][1] += __uint_as_float((a0.y - OFFSET_FP32) + b.y);
            acc[0][2] += __uint_as_float((a0.z - OFFSET_FP32) + b.z);
            acc[0][3] += __uint_as_float((a0.w - OFFSET_FP32) + b.w);
            acc[1][0] += __uint_as_float((a1.x - OFFSET_FP32) + b.x);
            acc[1][1] += __uint_as_float((a1.y - OFFSET_FP32) + b.y);
            acc[1][2] += __uint_as_float((a1.z - OFFSET_FP32) + b.z);
            acc[1][3] += __uint_as_float((a1.w - OFFSET_FP32) + b.w);
        }

        if (c + 1 < NC) __syncthreads();  // drains chunk c+1 (vmcnt(0)) + barrier
    }

    // ---- epilogue: direct coalesced stores, bias fused ----
    const int   p  = p0 + p_local;
    const float bv = bias[p];
    #pragma unroll
    for (int r = 0; r < TM; ++r) {
        out[(size_t)(m0 + r) * P + p] =
            (acc[r][0] + acc[r][1]) + (acc[r][2] + acc[r][3]) + bv;
    }
}

extern "C" void kernel_launch(void* const* d_in, const int* in_sizes, int n_in,
                              void* d_out, int out_size, void* d_ws, size_t ws_size,
                              hipStream_t stream) {
    const uint32_t* xb   = (const uint32_t*)d_in[0];  // x: (256,512) f32 bits
    const uint32_t* wb   = (const uint32_t*)d_in[1];  // weight: (512,512) f32 bits
    const float*    bias = (const float*)d_in[2];     // (512,)
    float*          out  = (float*)d_out;             // (256,512) f32

    // no memset: every output element is written exactly once by its block
    dim3 grid(M / BM, P / BP);  // (32, 8) = 256 blocks = 1 per CU
    dim3 block(256);            // 4 waves = 1 wave/SIMD
    lmul_linear_kernel<<<grid, block, 0, stream>>>(xb, wb, bias, out);
}

// Round 2
// 64.132 us; speedup vs baseline: 1.0580x; 1.0580x over previous
//
#include <hip/hip_runtime.h>
#include <stdint.h>

// out[m,p] = sum_k f32(bits(x[m,k]) + bits(weight[p,k]) - OFFSET) + bias[p]
// m=256, n=512, p=512. Pure VALU workload (uint add on bit patterns -> no MFMA).
//
// R7: single dispatch, no memset, no atomics -- k-split moved INSIDE the block.
//  Post-mortem of R6 (+3.5us): TM=2 made it LDS-bound (4 waves x 128 steps x
//  12cyc = 6144 cyc/CU > 4096 VALU floor) and 1 wave/SIMD exposed every stall.
//  Constraint: 2 waves/SIMD chip-wide => 131072 threads => T*Kper = 512.
//  TM=4 (LDS 3072 < 4096 floor) forces Kper=128 = 4-way k-split. R5 split
//  across blocks (atomics+memset); R7 splits across WAVES of a 512-thr block:
//  - grid 32x8 = 256 blocks, 1/CU, 8 waves = 2 waves/SIMD (R5's occupancy).
//  - wave wq: ks=wq&3 (k-group), mq=wq>>2 (row half). Group ks owns k-stripes
//    {64*ks..+63} u {256+64*ks..+63}; each (ks,mq) wave: 4 m-rows x 64 p.
//  - block owns its 8x64 output tile fully: partials combined via an 8KB LDS
//    reduction + ONE plain coalesced store. Memset dispatch + 524K-atomic
//    tail both gone.
//  - w tile [64p][512k] = 128KB staged via global_load_lds width=16 in 2
//    halves (k 0..255, 256..511): half B issued right after the half-A
//    barrier, hides under phase-B compute (2048 cyc/SIMD vs ~1100 cyc BW).
//    Only half A (~0.5us) is exposed.
//  - same measured-0-conflict swizzle family as R5: LDS granule g of row r
//    holds logical granule g^(r&7); gll writes linearly so the XOR is
//    pre-applied on the per-lane GLOBAL src address (both-sides rule).
//    Compute reads granule (j^rot), rot=lane&7: bank = 4*(j^rot) mod 32,
//    row-independent -- 8 lanes/bank-quad, distinct quads, R5-verified free.
//  - OFFSET fold on the wave-uniform x values (SALU, free beside 32 VALU/step).
//
// Measurement context: ~60us of dur_us is fixed harness cost (268MB ws
// re-poison = 40us at 84% HBM peak). R5 controllable chain ~4.4us
// (memset dispatch + kernel w/ atomic tail); this targets ~3us in ONE dispatch.

#define OFFSET_FP32 1064828928u

constexpr int M = 256;
constexpr int N = 512;
constexpr int P = 512;

constexpr int BM = 8;    // m rows per block
constexpr int BP = 64;   // p cols per block
constexpr int TM = 4;    // m rows per thread

__global__ __launch_bounds__(512) void lmul_linear_kernel(
    const uint32_t* __restrict__ xb,   // [M][N] bit patterns of x
    const uint32_t* __restrict__ wb,   // [P][N] bit patterns of weight
    const float*    __restrict__ bias, // [P]
    float*          __restrict__ out)  // [M][P]
{
    __shared__ uint32_t Bs[BP][N];        // 64 x 512 dwords = 128 KB
    __shared__ float    Red[4][BM][BP];   // k-group partials, 8 KB

    const int tid  = threadIdx.x;
    const int lane = tid & 63;                                     // = p_local
    const int wq   = __builtin_amdgcn_readfirstlane(tid >> 6);     // wave 0..7
    const int ks   = wq & 3;   // k-group
    const int mq   = wq >> 2;  // row half

    const int p0 = blockIdx.y * BP;
    const int m0 = blockIdx.x * BM + mq * TM;

    // ---- stage half h (granules 64h..64h+63 of every row): 64 x 1KB gll
    //      calls; wave wq stages rows wq*8..wq*8+7. LDS dst is wave-uniform
    //      (hw adds lane*16); swizzle rides on the per-lane global src. ----
    auto stage = [&](int h) {
        #pragma unroll
        for (int i = 0; i < 8; ++i) {
            const int row = wq * 8 + i;
            const uint32_t* src = wb + (size_t)(p0 + row) * N
                                + (size_t)(h * 64 + (lane ^ (row & 7))) * 4;
            uint32_t* dst = &Bs[row][h * 256];
            __builtin_amdgcn_global_load_lds(
                (const __attribute__((address_space(1))) uint32_t*)src,
                (__attribute__((address_space(3))) uint32_t*)dst,
                16, 0, 0);
        }
    };

    float acc[TM][4] = {};
    const int rot = lane & 7;

    const uint32_t* xr0 = xb + (size_t)(m0 + 0) * N;
    const uint32_t* xr1 = xb + (size_t)(m0 + 1) * N;
    const uint32_t* xr2 = xb + (size_t)(m0 + 2) * N;
    const uint32_t* xr3 = xb + (size_t)(m0 + 3) * N;

    // ---- compute stripe of half h for this k-group: 16 steps x
    //      (1 ds_read_b128 + 4 uniform uint4 a-loads [scalar path] + 32 VALU) ----
    auto compute = [&](int h) {
        const uint32_t* brow = &Bs[lane][(h * 64 + ks * 16) * 4];
        const int xoff = h * 256 + ks * 64;
        #pragma unroll 8
        for (int j = 0; j < 16; ++j) {
            const uint4 b  = *(const uint4*)&brow[(j ^ rot) * 4];
            const uint4 a0 = *(const uint4*)(xr0 + xoff + j * 4);
            const uint4 a1 = *(const uint4*)(xr1 + xoff + j * 4);
            const uint4 a2 = *(const uint4*)(xr2 + xoff + j * 4);
            const uint4 a3 = *(const uint4*)(xr3 + xoff + j * 4);
            acc[0][0] += __uint_as_float((a0.x - OFFSET_FP32) + b.x);
            acc[0][1] += __uint_as_float((a0.y - OFFSET_FP32) + b.y);
            acc[0][2] += __uint_as_float((a0.z - OFFSET_FP32) + b.z);
            acc[0][3] += __uint_as_float((a0.w - OFFSET_FP32) + b.w);
            acc[1][0] += __uint_as_float((a1.x - OFFSET_FP32) + b.x);
            acc[1][1] += __uint_as_float((a1.y - OFFSET_FP32) + b.y);
            acc[1][2] += __uint_as_float((a1.z - OFFSET_FP32) + b.z);
            acc[1][3] += __uint_as_float((a1.w - OFFSET_FP32) + b.w);
            acc[2][0] += __uint_as_float((a2.x - OFFSET_FP32) + b.x);
            acc[2][1] += __uint_as_float((a2.y - OFFSET_FP32) + b.y);
            acc[2][2] += __uint_as_float((a2.z - OFFSET_FP32) + b.z);
            acc[2][3] += __uint_as_float((a2.w - OFFSET_FP32) + b.w);
            acc[3][0] += __uint_as_float((a3.x - OFFSET_FP32) + b.x);
            acc[3][1] += __uint_as_float((a3.y - OFFSET_FP32) + b.y);
            acc[3][2] += __uint_as_float((a3.z - OFFSET_FP32) + b.z);
            acc[3][3] += __uint_as_float((a3.w - OFFSET_FP32) + b.w);
        }
    };

    stage(0);
    __syncthreads();          // vmcnt(0) drain: half A resident
    stage(1);                 // async issue, hides under phase-B compute
    compute(0);
    __syncthreads();          // vmcnt(0) drain: half B resident
    compute(1);

    // ---- per-output 4-way k-group reduction in LDS, then one plain store ----
    #pragma unroll
    for (int r = 0; r < TM; ++r)
        Red[ks][mq * TM + r][lane] =
            (acc[r][0] + acc[r][1]) + (acc[r][2] + acc[r][3]);
    __syncthreads();

    const int rr = tid >> 6;          // 0..7: local output row
    const int p  = p0 + lane;
    const float s = (Red[0][rr][lane] + Red[1][rr][lane])
                  + (Red[2][rr][lane] + Red[3][rr][lane]);
    out[(size_t)(blockIdx.x * BM + rr) * P + p] = s + bias[p];
}

extern "C" void kernel_launch(void* const* d_in, const int* in_sizes, int n_in,
                              void* d_out, int out_size, void* d_ws, size_t ws_size,
                              hipStream_t stream) {
    const uint32_t* xb   = (const uint32_t*)d_in[0];  // x: (256,512) f32 bits
    const uint32_t* wb   = (const uint32_t*)d_in[1];  // weight: (512,512) f32 bits
    const float*    bias = (const float*)d_in[2];     // (512,)
    float*          out  = (float*)d_out;             // (256,512) f32

    // single dispatch: every output written exactly once by its owning block
    dim3 grid(M / BM, P / BP);  // (32, 8) = 256 blocks = 1 per CU
    dim3 block(512);            // 8 waves = 2 waves/SIMD
    lmul_linear_kernel<<<grid, block, 0, stream>>>(xb, wb, bias, out);
}